// Round 1
// baseline (655.060 us; speedup 1.0000x reference)
//
#include <hip/hip_runtime.h>
#include <math.h>

// Problem constants (from reference)
constexpr int NP = 20;   // N_PRED
constexpr int NL = 12;   // L
// LAMBDA_POS = LAMBDA_RAD = LAMBDA_UNPAIR = 0.5, EPS = 1e-6

__global__ __launch_bounds__(256) void myloss_kernel(
    const float4* __restrict__ pred,    // (B, 20, 4) as float4
    const float4* __restrict__ label,   // (B, 12, 4) as float4
    float* __restrict__ out,            // (B,)
    int B)
{
    // The argmin over cost is bit-sensitive: numpy computes mul/mul/add with
    // no FMA contraction. Pin contraction off so our cost is bit-identical
    // and no argmin flips occur (a flip costs O(1) error via the log term).
#pragma clang fp contract(off)
    int b = blockIdx.x * blockDim.x + threadIdx.x;
    if (b >= B) return;

    const float4* p4 = pred  + (size_t)b * NP;
    const float4* l4 = label + (size_t)b * NL;

    // Stage this batch's 20 preds in registers; precompute unpair terms.
    float px[NP], py[NP], pr[NP], pq[NP], up[NP];
#pragma unroll
    for (int j = 0; j < NP; ++j) {
        float4 v = p4[j];
        px[j] = v.x; py[j] = v.y; pr[j] = v.z; pq[j] = v.w;
        // (-log(1 - q + eps) + 0.5*r) * 0.5
        up[j] = (-logf(1.0f - v.w + 1e-6f) + 0.5f * v.z) * 0.5f;
    }

    float lp = 0.0f;        // pair loss accumulator
    unsigned mask = 0u;     // which preds got matched
    for (int l = 0; l < NL; ++l) {
        float4 lv = l4[l];
        float best = INFINITY;
        float bq = 0.0f;    // prob of best pred
        unsigned bbit = 0u; // bit of best pred
#pragma unroll
        for (int p = 0; p < NP; ++p) {
            float dx = lv.x - px[p];
            float dy = lv.y - py[p];
            float dist = sqrtf(dx * dx + dy * dy);   // precise: matches np
            float rd = fabsf(lv.z - pr[p]);
            float c = 0.5f * dist + 0.5f * rd;
            bool lt = c < best;                      // strict < = first-min, like argmin
            best = lt ? c : best;
            bq   = lt ? pq[p] : bq;
            bbit = lt ? (1u << p) : bbit;
        }
        // min cost IS 0.5*mdist + 0.5*mrdiff (identical float ops); add -log(q+eps)
        lp += best - logf(bq + 1e-6f);
        mask |= bbit;
    }

    float lu = 0.0f;
#pragma unroll
    for (int p = 0; p < NP; ++p) {
        lu += (mask & (1u << p)) ? 0.0f : up[p];
    }

    out[b] = lp / 12.0f + lu / 8.0f;  // / L  +  / (N_PRED - L)
}

extern "C" void kernel_launch(void* const* d_in, const int* in_sizes, int n_in,
                              void* d_out, int out_size, void* d_ws, size_t ws_size,
                              hipStream_t stream) {
    const float4* pred  = (const float4*)d_in[0];
    const float4* label = (const float4*)d_in[1];
    float* out = (float*)d_out;
    int B = out_size;   // one output per batch element
    int threads = 256;
    int blocks = (B + threads - 1) / threads;
    hipLaunchKernelGGL(myloss_kernel, dim3(blocks), dim3(threads), 0, stream,
                       pred, label, out, B);
}

// Round 2
// 608.485 us; speedup vs baseline: 1.0765x; 1.0765x over previous
//
#include <hip/hip_runtime.h>
#include <math.h>

// Problem constants (from reference)
constexpr int NP = 20;   // N_PRED
constexpr int NL = 12;   // L
// LAMBDA_POS = LAMBDA_RAD = LAMBDA_UNPAIR = 0.5, EPS = 1e-6

// Fast natural log: v_log_f32 (log2, ~1 ulp) * ln(2). Used ONLY for loss
// values (never the argmin), where bf16-granularity comparison gives huge
// slack; error ~2e-6 absolute.
__device__ __forceinline__ float fast_log(float x) {
    return __builtin_amdgcn_logf(x) * 0.69314718055994530942f;
}

__global__ __launch_bounds__(256) void myloss_kernel(
    const float4* __restrict__ pred,    // (B, 20, 4) as float4
    const float4* __restrict__ label,   // (B, 12, 4) as float4
    float* __restrict__ out,            // (B,)
    int B)
{
    int b = blockIdx.x * blockDim.x + threadIdx.x;
    if (b >= B) return;

    const float4* p4 = pred  + (size_t)b * NP;
    const float4* l4 = label + (size_t)b * NL;

    // Stage this batch's 20 preds in registers (exact values: q's low bits
    // matter for the -log(1-q+eps) unpair term when q ~ 1).
    float px[NP], py[NP], pr[NP], pq[NP];
#pragma unroll
    for (int j = 0; j < NP; ++j) {
        float4 v = p4[j];
        px[j] = v.x; py[j] = v.y; pr[j] = v.z; pq[j] = v.w;
    }

    float lp = 0.0f;        // pair loss accumulator
    unsigned mask = 0u;     // which preds got matched
    // unroll 2: full unroll of 12 would blow the 32 KB I$ (~34 KB body).
#pragma unroll 2
    for (int l = 0; l < NL; ++l) {
        float4 lv = l4[l];
        // Argmin over s = dist + rdiff. Bit-exact vs ref's 0.5*dist+0.5*rd:
        // both 0.5* products are exact, so RN(0.5d+0.5r) = 0.5*RN(d+r) —
        // identical ordering, and pair term = 0.5*s_min exactly.
        // 4 independent chains of 5 (contiguous index ranges) for ILP;
        // strict < = first-index-wins within a chain, merges prefer the
        // lower-index chain on ties -> matches np.argmin tie-breaking.
        float    bs[4];
        float    bq[4];
        unsigned bb[4];
#pragma unroll
        for (int c = 0; c < 4; ++c) { bs[c] = INFINITY; bq[c] = 0.0f; bb[c] = 0u; }
#pragma unroll
        for (int i = 0; i < 5; ++i) {
#pragma unroll
            for (int c = 0; c < 4; ++c) {
                int p = c * 5 + i;
                float s;
                {
                    // argmin-critical path: no FMA contraction (numpy does
                    // mul/mul/add with separate roundings), precise sqrtf
                    // (= np.sqrt, correctly rounded).
#pragma clang fp contract(off)
                    float dx = lv.x - px[p];
                    float dy = lv.y - py[p];
                    float d2 = dx * dx + dy * dy;
                    float dist = sqrtf(d2);
                    s = dist + fabsf(lv.z - pr[p]);
                }
                bool lt = s < bs[c];
                bs[c] = lt ? s : bs[c];
                bq[c] = lt ? pq[p] : bq[c];
                bb[c] = lt ? (1u << p) : bb[c];
            }
        }
        // merge: ties keep the lower-index chain
        bool m01 = bs[1] < bs[0];
        float sa = m01 ? bs[1] : bs[0];
        float qa = m01 ? bq[1] : bq[0];
        unsigned ba = m01 ? bb[1] : bb[0];
        bool m23 = bs[3] < bs[2];
        float sb = m23 ? bs[3] : bs[2];
        float qb = m23 ? bq[3] : bq[2];
        unsigned bbm = m23 ? bb[3] : bb[2];
        bool mf = sb < sa;
        float sm = mf ? sb : sa;
        float qm = mf ? qb : qa;
        unsigned bm = mf ? bbm : ba;

        lp += 0.5f * sm - fast_log(qm + 1e-6f);
        mask |= bm;
    }

    // Unpair: sum over unmatched preds of (-log(1-q+eps) + 0.5*r) * 0.5
    float lu = 0.0f;
#pragma unroll
    for (int p = 0; p < NP; ++p) {
        float t = (-fast_log(1.0f - pq[p] + 1e-6f) + 0.5f * pr[p]) * 0.5f;
        lu += (mask & (1u << p)) ? 0.0f : t;
    }

    out[b] = lp * (1.0f / 12.0f) + lu * 0.125f;  // /L + /(N_PRED-L)
}

extern "C" void kernel_launch(void* const* d_in, const int* in_sizes, int n_in,
                              void* d_out, int out_size, void* d_ws, size_t ws_size,
                              hipStream_t stream) {
    const float4* pred  = (const float4*)d_in[0];
    const float4* label = (const float4*)d_in[1];
    float* out = (float*)d_out;
    int B = out_size;
    int threads = 256;
    int blocks = (B + threads - 1) / threads;
    hipLaunchKernelGGL(myloss_kernel, dim3(blocks), dim3(threads), 0, stream,
                       pred, label, out, B);
}